// Round 1
// baseline (161.643 us; speedup 1.0000x reference)
//
#include <hip/hip_runtime.h>
#include <hip/hip_bf16.h>
#include <math.h>

typedef __bf16 v8bf __attribute__((ext_vector_type(8)));
typedef float  v4f  __attribute__((ext_vector_type(4)));

#define GPTR(p) ((const __attribute__((address_space(1))) void*)(p))
#define LPTR(p) ((__attribute__((address_space(3))) void*)(p))

// ---------------- f32 -> bf16 elementwise (vectorized, n % 4 == 0) ----------
__global__ void f32_to_bf16_k(const float* __restrict__ in,
                              __hip_bfloat16* __restrict__ out, int n4) {
    int i = blockIdx.x * blockDim.x + threadIdx.x;
    if (i >= n4) return;
    float4 v = ((const float4*)in)[i];
    __hip_bfloat16 h[4] = {__float2bfloat16(v.x), __float2bfloat16(v.y),
                           __float2bfloat16(v.z), __float2bfloat16(v.w)};
    ((short4*)out)[i] = *(short4*)h;
}

// ---------------- W[K][N] f32 -> Wt[N][K] bf16 (32x32 LDS tile) -------------
__global__ __launch_bounds__(256)
void transpose_to_bf16_k(const float* __restrict__ W,
                         __hip_bfloat16* __restrict__ Wt, int K, int N) {
    __shared__ float t[32][33];
    int kt = blockIdx.x * 32, nt = blockIdx.y * 32;
    int tx = threadIdx.x, ty = threadIdx.y; // (32,8)
#pragma unroll
    for (int i = 0; i < 4; ++i)
        t[ty + i * 8][tx] = W[(size_t)(kt + ty + i * 8) * N + nt + tx];
    __syncthreads();
#pragma unroll
    for (int i = 0; i < 4; ++i)
        Wt[(size_t)(nt + ty + i * 8) * K + kt + tx] =
            __float2bfloat16(t[tx][ty + i * 8]);
}

// ---------------- NT GEMM: C[M][N] = A[M][K] * Bt[N][K]^T (+bias, relu) -----
// BM=BN=128, BK=64, 256 threads = 4 waves (2x2 wave grid), 16x16x32 bf16 MFMA.
template <int RELU, int HAS_BIAS, int OUT_F32>
__global__ __launch_bounds__(256)
void gemm_bt(const __hip_bfloat16* __restrict__ A,
             const __hip_bfloat16* __restrict__ Bt,
             const float* __restrict__ bias, void* __restrict__ Cout,
             int M, int N, int K) {
    __shared__ __align__(16) __hip_bfloat16 As[128 * 64];
    __shared__ __align__(16) __hip_bfloat16 Bs[128 * 64];
    const int tid  = threadIdx.x;
    const int wid  = tid >> 6;
    const int lane = tid & 63;
    const int wr   = wid >> 1, wc = wid & 1;
    const int bm   = blockIdx.x * 128;
    const int bn   = blockIdx.y * 128;

    v4f acc[4][4] = {};

    const int crow = lane >> 3;        // 0..7  row-within-chunk
    const int ccol = (lane & 7) * 8;   // 0..56 col (bf16 elems)

    for (int k0 = 0; k0 < K; k0 += 64) {
        // stage A and B tiles: 16 chunks of 1KB each, 4 chunks/wave
#pragma unroll
        for (int i = 0; i < 4; ++i) {
            int c = wid * 4 + i;
            const __hip_bfloat16* ga =
                A + (size_t)(bm + c * 8 + crow) * K + k0 + ccol;
            __builtin_amdgcn_global_load_lds(GPTR(ga), LPTR(&As[c * 512]), 16, 0, 0);
            const __hip_bfloat16* gb =
                Bt + (size_t)(bn + c * 8 + crow) * K + k0 + ccol;
            __builtin_amdgcn_global_load_lds(GPTR(gb), LPTR(&Bs[c * 512]), 16, 0, 0);
        }
        __syncthreads();
#pragma unroll
        for (int kk = 0; kk < 64; kk += 32) {
            v8bf a[4], b[4];
#pragma unroll
            for (int i = 0; i < 4; ++i) {
                int ra = wr * 64 + i * 16 + (lane & 15);
                a[i] = *(const v8bf*)&As[ra * 64 + kk + (lane >> 4) * 8];
                int rb = wc * 64 + i * 16 + (lane & 15);
                b[i] = *(const v8bf*)&Bs[rb * 64 + kk + (lane >> 4) * 8];
            }
#pragma unroll
            for (int i = 0; i < 4; ++i)
#pragma unroll
                for (int j = 0; j < 4; ++j)
                    acc[i][j] = __builtin_amdgcn_mfma_f32_16x16x32_bf16(
                        a[i], b[j], acc[i][j], 0, 0, 0);
        }
        __syncthreads();
    }

    // epilogue: C/D layout col=lane&15, row=(lane>>4)*4+reg
#pragma unroll
    for (int i = 0; i < 4; ++i) {
        int rowb = bm + wr * 64 + i * 16 + (lane >> 4) * 4;
#pragma unroll
        for (int j = 0; j < 4; ++j) {
            int col = bn + wc * 64 + j * 16 + (lane & 15);
            float bv = HAS_BIAS ? bias[col] : 0.f;
#pragma unroll
            for (int r = 0; r < 4; ++r) {
                float v = acc[i][j][r] + bv;
                if (RELU) v = fmaxf(v, 0.f);
                size_t idx = (size_t)(rowb + r) * N + col;
                if (OUT_F32)
                    ((float*)Cout)[idx] = v;
                else
                    ((__hip_bfloat16*)Cout)[idx] = __float2bfloat16(v);
            }
        }
    }
}

// ---------------- row-wise L2 normalize: z[4096][128] f32 -> bf16 -----------
__global__ __launch_bounds__(256)
void l2norm_bf16_k(const float* __restrict__ z, __hip_bfloat16* __restrict__ out) {
    int row  = blockIdx.x * 4 + (threadIdx.x >> 6);
    int lane = threadIdx.x & 63;
    const float* p = z + (size_t)row * 128;
    float2 v = *(const float2*)&p[lane * 2];
    float ss = v.x * v.x + v.y * v.y;
#pragma unroll
    for (int d = 32; d > 0; d >>= 1) ss += __shfl_xor(ss, d, 64);
    float inv = 1.0f / fmaxf(sqrtf(ss), 1e-12f);
    __hip_bfloat162 pr;
    pr.x = __float2bfloat16(v.x * inv);
    pr.y = __float2bfloat16(v.y * inv);
    *(__hip_bfloat162*)&out[(size_t)row * 128 + lane * 2] = pr;
}

// ---------------- per-row logsumexp -> mi -----------------------------------
__global__ __launch_bounds__(256)
void mi_k(const float* __restrict__ scores, float* __restrict__ mi) {
    int row = blockIdx.x;
    int tid = threadIdx.x;
    const float* r = scores + (size_t)row * 4096;
    float4 v[4];
#pragma unroll
    for (int p = 0; p < 4; ++p) v[p] = *(const float4*)&r[p * 1024 + tid * 4];
    float m = -1e30f;
#pragma unroll
    for (int p = 0; p < 4; ++p)
        m = fmaxf(m, fmaxf(fmaxf(v[p].x, v[p].y), fmaxf(v[p].z, v[p].w)));
    __shared__ float red[4];
    __shared__ float red2[4];
#pragma unroll
    for (int d = 32; d > 0; d >>= 1) m = fmaxf(m, __shfl_xor(m, d, 64));
    if ((tid & 63) == 0) red[tid >> 6] = m;
    __syncthreads();
    m = fmaxf(fmaxf(red[0], red[1]), fmaxf(red[2], red[3]));
    float s = 0.f;
#pragma unroll
    for (int p = 0; p < 4; ++p)
        s += __expf(v[p].x - m) + __expf(v[p].y - m) +
             __expf(v[p].z - m) + __expf(v[p].w - m);
#pragma unroll
    for (int d = 32; d > 0; d >>= 1) s += __shfl_xor(s, d, 64);
    if ((tid & 63) == 0) red2[tid >> 6] = s;
    __syncthreads();
    if (tid == 0) {
        float lse = m + logf(red2[0] + red2[1] + red2[2] + red2[3]);
        mi[row] = 8.317766166719343f + r[row] - lse; // log(4096) + diag - lse
    }
}

// ---------------------------------------------------------------------------
extern "C" void kernel_launch(void* const* d_in, const int* in_sizes, int n_in,
                              void* d_out, int out_size, void* d_ws, size_t ws_size,
                              hipStream_t stream) {
    const float* x   = (const float*)d_in[0];
    const float* y   = (const float*)d_in[1];
    const float* sW1 = (const float*)d_in[2];
    const float* sb1 = (const float*)d_in[3];
    const float* sW2 = (const float*)d_in[4];
    const float* sb2 = (const float*)d_in[5];
    const float* sW3 = (const float*)d_in[6];
    const float* sb3 = (const float*)d_in[7];
    const float* kW1 = (const float*)d_in[8];
    const float* kb1 = (const float*)d_in[9];
    const float* kW2 = (const float*)d_in[10];
    const float* kb2 = (const float*)d_in[11];
    const float* kW3 = (const float*)d_in[12];
    const float* kb3 = (const float*)d_in[13];

    float* out = (float*)d_out;                   // scores [4096][4096]
    float* mi  = out + (size_t)4096 * 4096;       // mi [4096]

    char* ws = (char*)d_ws;
    auto alloc = [&](size_t bytes) {
        char* p = ws;
        ws += (bytes + 255) & ~(size_t)255;
        return p;
    };
    __hip_bfloat16* xb   = (__hip_bfloat16*)alloc((size_t)4096 * 256 * 2);
    __hip_bfloat16* yb   = (__hip_bfloat16*)alloc((size_t)4096 * 64 * 2);
    __hip_bfloat16* sW1t = (__hip_bfloat16*)alloc((size_t)1024 * 256 * 2);
    __hip_bfloat16* sW2t = (__hip_bfloat16*)alloc((size_t)1024 * 1024 * 2);
    __hip_bfloat16* sW3t = (__hip_bfloat16*)alloc((size_t)128 * 1024 * 2);
    __hip_bfloat16* kW1t = (__hip_bfloat16*)alloc((size_t)1024 * 64 * 2);
    __hip_bfloat16* kW2t = (__hip_bfloat16*)alloc((size_t)1024 * 1024 * 2);
    __hip_bfloat16* kW3t = (__hip_bfloat16*)alloc((size_t)128 * 1024 * 2);
    __hip_bfloat16* h1   = (__hip_bfloat16*)alloc((size_t)4096 * 1024 * 2);
    __hip_bfloat16* h2   = (__hip_bfloat16*)alloc((size_t)4096 * 1024 * 2);
    float*          zx   = (float*)alloc((size_t)4096 * 128 * 4);
    float*          zy   = (float*)alloc((size_t)4096 * 128 * 4);
    __hip_bfloat16* zxb  = (__hip_bfloat16*)alloc((size_t)4096 * 128 * 2);
    __hip_bfloat16* zyb  = (__hip_bfloat16*)alloc((size_t)4096 * 128 * 2);

    // ---- prep: casts + weight transposes ----
    f32_to_bf16_k<<<(4096 * 256 / 4 + 255) / 256, 256, 0, stream>>>(x, xb, 4096 * 256 / 4);
    f32_to_bf16_k<<<(4096 * 64 / 4 + 255) / 256, 256, 0, stream>>>(y, yb, 4096 * 64 / 4);
    transpose_to_bf16_k<<<dim3(8, 32),  dim3(32, 8), 0, stream>>>(sW1, sW1t, 256, 1024);
    transpose_to_bf16_k<<<dim3(32, 32), dim3(32, 8), 0, stream>>>(sW2, sW2t, 1024, 1024);
    transpose_to_bf16_k<<<dim3(32, 4),  dim3(32, 8), 0, stream>>>(sW3, sW3t, 1024, 128);
    transpose_to_bf16_k<<<dim3(2, 32),  dim3(32, 8), 0, stream>>>(kW1, kW1t, 64, 1024);
    transpose_to_bf16_k<<<dim3(32, 32), dim3(32, 8), 0, stream>>>(kW2, kW2t, 1024, 1024);
    transpose_to_bf16_k<<<dim3(32, 4),  dim3(32, 8), 0, stream>>>(kW3, kW3t, 1024, 128);

    // ---- state MLP ----
    gemm_bt<1, 1, 0><<<dim3(32, 8), 256, 0, stream>>>(xb, sW1t, sb1, h1, 4096, 1024, 256);
    gemm_bt<1, 1, 0><<<dim3(32, 8), 256, 0, stream>>>(h1, sW2t, sb2, h2, 4096, 1024, 1024);
    gemm_bt<0, 1, 1><<<dim3(32, 1), 256, 0, stream>>>(h2, sW3t, sb3, zx, 4096, 128, 1024);
    // ---- skill MLP (reuses h1/h2) ----
    gemm_bt<1, 1, 0><<<dim3(32, 8), 256, 0, stream>>>(yb, kW1t, kb1, h1, 4096, 1024, 64);
    gemm_bt<1, 1, 0><<<dim3(32, 8), 256, 0, stream>>>(h1, kW2t, kb2, h2, 4096, 1024, 1024);
    gemm_bt<0, 1, 1><<<dim3(32, 1), 256, 0, stream>>>(h2, kW3t, kb3, zy, 4096, 128, 1024);

    // ---- normalize ----
    l2norm_bf16_k<<<1024, 256, 0, stream>>>(zx, zxb);
    l2norm_bf16_k<<<1024, 256, 0, stream>>>(zy, zyb);

    // ---- scores = zx @ zy^T (f32 out to d_out) ----
    gemm_bt<0, 0, 1><<<dim3(32, 32), 256, 0, stream>>>(zxb, zyb, nullptr, out, 4096, 4096, 128);

    // ---- mi = log(B) + diag(log_softmax(scores)) ----
    mi_k<<<4096, 256, 0, stream>>>(out, mi);
}

// Round 2
// 90.391 us; speedup vs baseline: 1.7883x; 1.7883x over previous
//
#include <hip/hip_runtime.h>
#include <hip/hip_bf16.h>
#include <math.h>

typedef __bf16 v8bf __attribute__((ext_vector_type(8)));
typedef float  v4f  __attribute__((ext_vector_type(4)));

#define GPTR(p) ((const __attribute__((address_space(1))) void*)(p))
#define LPTR(p) ((__attribute__((address_space(3))) void*)(p))

// ---------------- casts: x and y f32 -> bf16 in one launch ------------------
__global__ __launch_bounds__(256)
void cast_xy_k(const float* __restrict__ x, const float* __restrict__ y,
               __hip_bfloat16* __restrict__ xb, __hip_bfloat16* __restrict__ yb,
               int nx4, int ntot4) {
    int i = blockIdx.x * 256 + threadIdx.x;
    if (i >= ntot4) return;
    const float* src; __hip_bfloat16* dst; int j;
    if (i < nx4) { src = x; dst = xb; j = i; }
    else         { src = y; dst = yb; j = i - nx4; }
    float4 v = ((const float4*)src)[j];
    __hip_bfloat16 h[4] = {__float2bfloat16(v.x), __float2bfloat16(v.y),
                           __float2bfloat16(v.z), __float2bfloat16(v.w)};
    ((short4*)dst)[j] = *(short4*)h;
}

// ---------------- all 6 weight transposes in one launch ---------------------
struct TransAll {
    const float* src[6];
    __hip_bfloat16* dst[6];
    int K[6], N[6];
};

__global__ __launch_bounds__(256)
void transpose_all_k(TransAll a) {
    int w = blockIdx.z;
    int K = a.K[w], N = a.N[w];
    int kt = blockIdx.x * 32, nt = blockIdx.y * 32;
    if (kt >= K || nt >= N) return;
    __shared__ float t[32][33];
    int tx = threadIdx.x & 31, ty = threadIdx.x >> 5; // (32,8)
    const float* W = a.src[w];
    __hip_bfloat16* Wt = a.dst[w];
#pragma unroll
    for (int i = 0; i < 4; ++i)
        t[ty + i * 8][tx] = W[(size_t)(kt + ty + i * 8) * N + nt + tx];
    __syncthreads();
#pragma unroll
    for (int i = 0; i < 4; ++i)
        Wt[(size_t)(nt + ty + i * 8) * K + kt + tx] =
            __float2bfloat16(t[tx][ty + i * 8]);
}

// ---------------- shared GEMM main loop (BM=BN=128, BK=64, 4 waves) ---------
__device__ __forceinline__ void gemm_mainloop(
    const __hip_bfloat16* __restrict__ A, const __hip_bfloat16* __restrict__ Bt,
    int lda, int ldb, int kbeg, int kend, int bm, int bn,
    int wid, int lane, int wr, int wc,
    __hip_bfloat16* As, __hip_bfloat16* Bs, v4f acc[4][4]) {
    const int crow = lane >> 3;       // 0..7
    const int ccol = (lane & 7) * 8;  // 0..56
    for (int k0 = kbeg; k0 < kend; k0 += 64) {
#pragma unroll
        for (int i = 0; i < 4; ++i) {
            int c = wid * 4 + i;
            __builtin_amdgcn_global_load_lds(
                GPTR(A + (size_t)(bm + c * 8 + crow) * lda + k0 + ccol),
                LPTR(As + c * 512), 16, 0, 0);
            __builtin_amdgcn_global_load_lds(
                GPTR(Bt + (size_t)(bn + c * 8 + crow) * ldb + k0 + ccol),
                LPTR(Bs + c * 512), 16, 0, 0);
        }
        __syncthreads();
#pragma unroll
        for (int kk = 0; kk < 64; kk += 32) {
            v8bf a[4], b[4];
#pragma unroll
            for (int i = 0; i < 4; ++i) {
                a[i] = *(const v8bf*)&As[(wr * 64 + i * 16 + (lane & 15)) * 64 + kk + (lane >> 4) * 8];
                b[i] = *(const v8bf*)&Bs[(wc * 64 + i * 16 + (lane & 15)) * 64 + kk + (lane >> 4) * 8];
            }
#pragma unroll
            for (int i = 0; i < 4; ++i)
#pragma unroll
                for (int j = 0; j < 4; ++j)
                    acc[i][j] = __builtin_amdgcn_mfma_f32_16x16x32_bf16(
                        a[i], b[j], acc[i][j], 0, 0, 0);
        }
        __syncthreads();
    }
}

// ---------------- L1/L2 MLP GEMMs (relu+bias, bf16 out, z = which MLP) ------
struct MlpArgs {
    const __hip_bfloat16* A[2];
    const __hip_bfloat16* B[2];
    const float* bias[2];
    __hip_bfloat16* C[2];
    int K[2];
};

__global__ __launch_bounds__(256)
void gemm_mlp_k(MlpArgs args) {
    __shared__ __align__(16) __hip_bfloat16 As[128 * 64], Bs[128 * 64];
    const int z = blockIdx.z;
    const int tid = threadIdx.x, wid = tid >> 6, lane = tid & 63;
    const int wr = wid >> 1, wc = wid & 1;
    const int bm = blockIdx.x * 128, bn = blockIdx.y * 128;
    const int K = args.K[z];
    v4f acc[4][4] = {};
    gemm_mainloop(args.A[z], args.B[z], K, K, 0, K, bm, bn, wid, lane, wr, wc,
                  As, Bs, acc);
    const float* bias = args.bias[z];
    __hip_bfloat16* C = args.C[z];
#pragma unroll
    for (int i = 0; i < 4; ++i) {
        int rowb = bm + wr * 64 + i * 16 + (lane >> 4) * 4;
#pragma unroll
        for (int j = 0; j < 4; ++j) {
            int col = bn + wc * 64 + j * 16 + (lane & 15);
            float bv = bias[col];
#pragma unroll
            for (int r = 0; r < 4; ++r) {
                float v = fmaxf(acc[i][j][r] + bv, 0.f);
                C[(size_t)(rowb + r) * 1024 + col] = __float2bfloat16(v);
            }
        }
    }
}

// ---------------- L3 GEMMs, split-K x4, f32 partials ------------------------
struct L3Args {
    const __hip_bfloat16* A[2];
    const __hip_bfloat16* B[2];
    float* part; // [2][4][4096][128]
};

__global__ __launch_bounds__(256)
void gemm_l3_k(L3Args args) {
    __shared__ __align__(16) __hip_bfloat16 As[128 * 64], Bs[128 * 64];
    const int z = blockIdx.z, sp = blockIdx.y;
    const int tid = threadIdx.x, wid = tid >> 6, lane = tid & 63;
    const int wr = wid >> 1, wc = wid & 1;
    const int bm = blockIdx.x * 128;
    v4f acc[4][4] = {};
    gemm_mainloop(args.A[z], args.B[z], 1024, 1024, sp * 256, sp * 256 + 256,
                  bm, 0, wid, lane, wr, wc, As, Bs, acc);
    float* P = args.part + (size_t)(z * 4 + sp) * 4096 * 128;
#pragma unroll
    for (int i = 0; i < 4; ++i) {
        int rowb = bm + wr * 64 + i * 16 + (lane >> 4) * 4;
#pragma unroll
        for (int j = 0; j < 4; ++j) {
            int col = wc * 64 + j * 16 + (lane & 15);
#pragma unroll
            for (int r = 0; r < 4; ++r)
                P[(size_t)(rowb + r) * 128 + col] = acc[i][j][r];
        }
    }
}

// ---------------- reduce split-K partials + bias + L2-normalize -> bf16 -----
__global__ __launch_bounds__(256)
void norm_k(const float* __restrict__ part, const float* __restrict__ sb3,
            const float* __restrict__ kb3,
            __hip_bfloat16* __restrict__ zxb, __hip_bfloat16* __restrict__ zyb) {
    int row  = blockIdx.x * 4 + (threadIdx.x >> 6); // 0..8191
    int lane = threadIdx.x & 63;
    int g = row >> 12;       // 0: state, 1: skill
    int r = row & 4095;
    const float* bias = g ? kb3 : sb3;
    float vx = bias[lane * 2], vy = bias[lane * 2 + 1];
#pragma unroll
    for (int s = 0; s < 4; ++s) {
        float2 p = *(const float2*)&part[((size_t)(g * 4 + s) * 4096 + r) * 128 + lane * 2];
        vx += p.x; vy += p.y;
    }
    float ss = vx * vx + vy * vy;
#pragma unroll
    for (int d = 32; d > 0; d >>= 1) ss += __shfl_xor(ss, d, 64);
    float inv = 1.0f / fmaxf(sqrtf(ss), 1e-12f);
    __hip_bfloat162 pr;
    pr.x = __float2bfloat16(vx * inv);
    pr.y = __float2bfloat16(vy * inv);
    __hip_bfloat16* out = g ? zyb : zxb;
    *(__hip_bfloat162*)&out[(size_t)r * 128 + lane * 2] = pr;
}

// ---------------- scores GEMM + fused per-row partial exp-sums --------------
// scores in [-1,1] (cosine/TEMP), so lse = 1 + log(sum exp(s-1)) needs no max.
__global__ __launch_bounds__(256)
void gemm_scores_k(const __hip_bfloat16* __restrict__ zxb,
                   const __hip_bfloat16* __restrict__ zyb,
                   float* __restrict__ out, float* __restrict__ esum) {
    __shared__ __align__(16) __hip_bfloat16 As[128 * 64], Bs[128 * 64];
    __shared__ float rowsum[2][128];
    const int tid = threadIdx.x, wid = tid >> 6, lane = tid & 63;
    const int wr = wid >> 1, wc = wid & 1;
    const int bm = blockIdx.x * 128, bn = blockIdx.y * 128;
    v4f acc[4][4] = {};
    gemm_mainloop(zxb, zyb, 128, 128, 0, 128, bm, bn, wid, lane, wr, wc,
                  As, Bs, acc);
#pragma unroll
    for (int i = 0; i < 4; ++i) {
        int rowb = bm + wr * 64 + i * 16 + (lane >> 4) * 4;
#pragma unroll
        for (int r = 0; r < 4; ++r) {
            float s = 0.f;
#pragma unroll
            for (int j = 0; j < 4; ++j) {
                int col = bn + wc * 64 + j * 16 + (lane & 15);
                float v = acc[i][j][r];
                out[(size_t)(rowb + r) * 4096 + col] = v;
                s += __expf(v - 1.0f);
            }
#pragma unroll
            for (int m = 1; m < 16; m <<= 1) s += __shfl_xor(s, m, 64);
            if ((lane & 15) == 0)
                rowsum[wc][wr * 64 + i * 16 + (lane >> 4) * 4 + r] = s;
        }
    }
    __syncthreads();
    if (tid < 128)
        esum[(size_t)(bm + tid) * 32 + blockIdx.y] =
            rowsum[0][tid] + rowsum[1][tid];
}

// ---------------- mi from partial exp-sums + diag ---------------------------
__global__ __launch_bounds__(256)
void mi_k(const float* __restrict__ esum, const float* __restrict__ scores,
          float* __restrict__ mi) {
    int row = blockIdx.x * 256 + threadIdx.x;
    const float4* p = (const float4*)&esum[(size_t)row * 32];
    float s = 0.f;
#pragma unroll
    for (int i = 0; i < 8; ++i) { float4 v = p[i]; s += v.x + v.y + v.z + v.w; }
    float diag = scores[(size_t)row * 4096 + row];
    // mi = log(4096) + diag - (1 + log(sum))
    mi[row] = 8.317766166719343f + diag - 1.0f - logf(s);
}

// ---------------------------------------------------------------------------
extern "C" void kernel_launch(void* const* d_in, const int* in_sizes, int n_in,
                              void* d_out, int out_size, void* d_ws, size_t ws_size,
                              hipStream_t stream) {
    const float* x   = (const float*)d_in[0];
    const float* y   = (const float*)d_in[1];
    const float* sW1 = (const float*)d_in[2];
    const float* sb1 = (const float*)d_in[3];
    const float* sW2 = (const float*)d_in[4];
    const float* sb2 = (const float*)d_in[5];
    const float* sW3 = (const float*)d_in[6];
    const float* sb3 = (const float*)d_in[7];
    const float* kW1 = (const float*)d_in[8];
    const float* kb1 = (const float*)d_in[9];
    const float* kW2 = (const float*)d_in[10];
    const float* kb2 = (const float*)d_in[11];
    const float* kW3 = (const float*)d_in[12];
    const float* kb3 = (const float*)d_in[13];

    float* out = (float*)d_out;              // scores [4096][4096]
    float* mi  = out + (size_t)4096 * 4096;  // mi [4096]

    char* ws = (char*)d_ws;
    auto alloc = [&](size_t bytes) {
        char* p = ws;
        ws += (bytes + 255) & ~(size_t)255;
        return p;
    };
    __hip_bfloat16* xb   = (__hip_bfloat16*)alloc((size_t)4096 * 256 * 2);
    __hip_bfloat16* yb   = (__hip_bfloat16*)alloc((size_t)4096 * 64 * 2);
    __hip_bfloat16* sW1t = (__hip_bfloat16*)alloc((size_t)1024 * 256 * 2);
    __hip_bfloat16* sW2t = (__hip_bfloat16*)alloc((size_t)1024 * 1024 * 2);
    __hip_bfloat16* sW3t = (__hip_bfloat16*)alloc((size_t)128 * 1024 * 2);
    __hip_bfloat16* kW1t = (__hip_bfloat16*)alloc((size_t)1024 * 64 * 2);
    __hip_bfloat16* kW2t = (__hip_bfloat16*)alloc((size_t)1024 * 1024 * 2);
    __hip_bfloat16* kW3t = (__hip_bfloat16*)alloc((size_t)128 * 1024 * 2);
    __hip_bfloat16* h1s  = (__hip_bfloat16*)alloc((size_t)4096 * 1024 * 2);
    __hip_bfloat16* h1k  = (__hip_bfloat16*)alloc((size_t)4096 * 1024 * 2);
    __hip_bfloat16* h2s  = (__hip_bfloat16*)alloc((size_t)4096 * 1024 * 2);
    __hip_bfloat16* h2k  = (__hip_bfloat16*)alloc((size_t)4096 * 1024 * 2);
    float*          part = (float*)alloc((size_t)8 * 4096 * 128 * 4);
    float*          es   = (float*)alloc((size_t)4096 * 32 * 4);
    __hip_bfloat16* zxb  = (__hip_bfloat16*)alloc((size_t)4096 * 128 * 2);
    __hip_bfloat16* zyb  = (__hip_bfloat16*)alloc((size_t)4096 * 128 * 2);

    // K1: casts
    int nx4 = 4096 * 256 / 4, ny4 = 4096 * 64 / 4;
    cast_xy_k<<<(nx4 + ny4 + 255) / 256, 256, 0, stream>>>(x, y, xb, yb, nx4, nx4 + ny4);

    // K2: all weight transposes
    TransAll ta;
    ta.src[0] = sW1; ta.dst[0] = sW1t; ta.K[0] = 256;  ta.N[0] = 1024;
    ta.src[1] = sW2; ta.dst[1] = sW2t; ta.K[1] = 1024; ta.N[1] = 1024;
    ta.src[2] = sW3; ta.dst[2] = sW3t; ta.K[2] = 1024; ta.N[2] = 128;
    ta.src[3] = kW1; ta.dst[3] = kW1t; ta.K[3] = 64;   ta.N[3] = 1024;
    ta.src[4] = kW2; ta.dst[4] = kW2t; ta.K[4] = 1024; ta.N[4] = 1024;
    ta.src[5] = kW3; ta.dst[5] = kW3t; ta.K[5] = 1024; ta.N[5] = 128;
    transpose_all_k<<<dim3(32, 32, 6), 256, 0, stream>>>(ta);

    // K3: L1 GEMMs (both MLPs)
    MlpArgs l1;
    l1.A[0] = xb;  l1.B[0] = sW1t; l1.bias[0] = sb1; l1.C[0] = h1s; l1.K[0] = 256;
    l1.A[1] = yb;  l1.B[1] = kW1t; l1.bias[1] = kb1; l1.C[1] = h1k; l1.K[1] = 64;
    gemm_mlp_k<<<dim3(32, 8, 2), 256, 0, stream>>>(l1);

    // K4: L2 GEMMs (both MLPs)
    MlpArgs l2;
    l2.A[0] = h1s; l2.B[0] = sW2t; l2.bias[0] = sb2; l2.C[0] = h2s; l2.K[0] = 1024;
    l2.A[1] = h1k; l2.B[1] = kW2t; l2.bias[1] = kb2; l2.C[1] = h2k; l2.K[1] = 1024;
    gemm_mlp_k<<<dim3(32, 8, 2), 256, 0, stream>>>(l2);

    // K5: L3 GEMMs, split-K x4
    L3Args l3;
    l3.A[0] = h2s; l3.B[0] = sW3t;
    l3.A[1] = h2k; l3.B[1] = kW3t;
    l3.part = part;
    gemm_l3_k<<<dim3(32, 4, 2), 256, 0, stream>>>(l3);

    // K6: reduce + bias + normalize
    norm_k<<<2048, 256, 0, stream>>>(part, sb3, kb3, zxb, zyb);

    // K7: scores GEMM + fused partial exp-sums
    gemm_scores_k<<<dim3(32, 32), 256, 0, stream>>>(zxb, zyb, out, es);

    // K8: mi
    mi_k<<<16, 256, 0, stream>>>(es, out, mi);
}